// Round 6
// baseline (21592.429 us; speedup 1.0000x reference)
//
#include <hip/hip_runtime.h>
#include <hip/hip_cooperative_groups.h>

namespace cg = cooperative_groups;

// Problem dims
#define NB 64     // batch N
#define TS 512    // timesteps T
#define DI 512    // input I
#define DH 1024   // hidden H
#define DO 512    // output O

typedef __bf16 bf16x8 __attribute__((ext_vector_type(8)));
typedef float f32x4 __attribute__((ext_vector_type(4)));
typedef _Float16 f16x4 __attribute__((ext_vector_type(4)));
typedef int i32x4 __attribute__((ext_vector_type(4)));
typedef unsigned short u16x4 __attribute__((ext_vector_type(4)));

union V16 { i32x4 i; bf16x8 b; };

__device__ __forceinline__ float b2f(unsigned short u){
  union { unsigned int u; float f; } c; c.u = ((unsigned int)u) << 16; return c.f;
}
__device__ __forceinline__ unsigned short f2b(float f){
  union { float f; unsigned int u; } c; c.f = f;
  unsigned int x = c.u;
  return (unsigned short)((x + 0x7fffu + ((x >> 16) & 1u)) >> 16);
}

// Async global->LDS DMA, 16 B/lane. No dest VGPR => compiler cannot sink it.
// LDS dest = wave-uniform base + lane*16 [m104]; global src is per-lane.
__device__ __forceinline__ void gl_lds16(const void* g, void* l){
  __builtin_amdgcn_global_load_lds((const unsigned int*)g, (unsigned int*)l, 16, 0, 0);
}

// ---------------------------------------------------------------------------
// C = A @ B^T + bias.  B: [NC][K] fp32 weights -> bf16-hi in LDS.
// AD: A dtype 0=fp32 (split hi/lo bf16, near-exact), 2=fp16 (split hi/lo,
// EXACT: fp16 mantissa 11b = bf16hi 8b + residual <=3b).
// mode (C-row q -> A-row remap): 0 rA=q | 1 C rows [T,N], A rows [N,T]
//   | 2 C rows [N,T], A rows [T,N]
// flags: bits0-1 out {0:f32, 2:f16}; bit2: retanh.
// Tile 128x128, BK=64, 256 thr, 2x2 waves of 64x64 (4x4 16x16x32 frags).
// Proven engine (unchanged).
// ---------------------------------------------------------------------------
template<int AD>
__global__ __launch_bounds__(256) void gemm_bt(
    const void* __restrict__ Ain,
    const float* __restrict__ B,
    const float* __restrict__ bias,
    void* __restrict__ Cout,
    int K, int NC, int mode, int flags)
{
  __shared__ __align__(16) unsigned short As[2 * 128 * 72];
  __shared__ __align__(16) unsigned short Bs[128 * 72];
  constexpr int AS2 = 128 * 72;
  const int tid = threadIdx.x;
  const int q0 = blockIdx.y * 128;
  const int j0 = blockIdx.x * 128;
  const int w = tid >> 6, lane = tid & 63, quad = lane >> 4, lo4 = lane & 15;
  const int wm = w >> 1, wn = w & 1;
  f32x4 acc[4][4] = {};
  const int nkt = K >> 6;

  for (int kt = 0; kt < nkt; ++kt){
    __syncthreads();
    // B tile: 128 rows x 64 k, fp32 -> bf16 hi
    #pragma unroll
    for (int it = 0; it < 8; ++it){
      int idx = tid + it * 256;            // 2048 float4 chunks
      int row = idx >> 4, c4 = idx & 15;
      f32x4 f = *(const f32x4*)(B + (size_t)(j0 + row) * K + kt * 64 + c4 * 4);
      u16x4 h;
      #pragma unroll
      for (int j = 0; j < 4; ++j) h[j] = f2b(f[j]);
      *(u16x4*)(Bs + row * 72 + c4 * 4) = h;
    }
    // A tile: split hi/lo
    #pragma unroll
    for (int it = 0; it < 8; ++it){
      int idx = tid + it * 256;
      int row = idx >> 4, c4 = idx & 15;
      int q = q0 + row;
      int rA = (mode == 0) ? q : (mode == 1 ? (q & 63) * TS + (q >> 6)
                                            : (q & 511) * NB + (q >> 9));
      float fv[4];
      if (AD == 0){
        f32x4 f = *(const f32x4*)((const float*)Ain + (size_t)rA * K + kt * 64 + c4 * 4);
        #pragma unroll
        for (int j = 0; j < 4; ++j) fv[j] = f[j];
      } else {
        f16x4 f = *(const f16x4*)((const _Float16*)Ain + (size_t)rA * K + kt * 64 + c4 * 4);
        #pragma unroll
        for (int j = 0; j < 4; ++j) fv[j] = (float)f[j];
      }
      u16x4 hi, lo;
      #pragma unroll
      for (int j = 0; j < 4; ++j){
        unsigned short h = f2b(fv[j]);
        hi[j] = h;
        lo[j] = f2b(fv[j] - b2f(h));
      }
      *(u16x4*)(As + row * 72 + c4 * 4) = hi;
      *(u16x4*)(As + AS2 + row * 72 + c4 * 4) = lo;
    }
    __syncthreads();
    #pragma unroll
    for (int kk = 0; kk < 2; ++kk){
      V16 b[4];
      #pragma unroll
      for (int n = 0; n < 4; ++n)
        b[n].i = *(const i32x4*)(Bs + (64 * wn + 16 * n + lo4) * 72 + kk * 32 + quad * 8);
      V16 a[4], a2[4];
      #pragma unroll
      for (int m = 0; m < 4; ++m){
        a[m].i = *(const i32x4*)(As + (64 * wm + 16 * m + lo4) * 72 + kk * 32 + quad * 8);
        a2[m].i = *(const i32x4*)(As + AS2 + (64 * wm + 16 * m + lo4) * 72 + kk * 32 + quad * 8);
      }
      #pragma unroll
      for (int m = 0; m < 4; ++m)
        #pragma unroll
        for (int n = 0; n < 4; ++n){
          acc[m][n] = __builtin_amdgcn_mfma_f32_16x16x32_bf16(a[m].b, b[n].b, acc[m][n], 0, 0, 0);
          acc[m][n] = __builtin_amdgcn_mfma_f32_16x16x32_bf16(a2[m].b, b[n].b, acc[m][n], 0, 0, 0);
        }
    }
  }
  // epilogue: C/D layout col=lane&15, row=quad*4+reg  [m89]
  const int od = flags & 3;
  #pragma unroll
  for (int n = 0; n < 4; ++n){
    int col = j0 + 64 * wn + 16 * n + lo4;
    float bv = bias[col];
    #pragma unroll
    for (int m = 0; m < 4; ++m){
      int row = q0 + 64 * wm + 16 * m + quad * 4;
      #pragma unroll
      for (int r = 0; r < 4; ++r){
        float v = acc[m][n][r] + bv;
        if (flags & 4) v = tanhf(fmaxf(v, 0.0f));
        size_t o = (size_t)(row + r) * NC + col;
        if (od == 0) ((float*)Cout)[o] = v;
        else         ((_Float16*)Cout)[o] = (_Float16)v;
      }
    }
  }
}

// ---------------------------------------------------------------------------
// h0 fp32 -> hi/lo bf16 planes (65536 elements) into plane buffer 0.
// Block 0 additionally zeroes the 64 barrier flags.
// ---------------------------------------------------------------------------
__global__ __launch_bounds__(256) void split_h0(
    const float* __restrict__ h0, unsigned short* __restrict__ plane,
    unsigned* __restrict__ flags)
{
  int i = blockIdx.x * 256 + threadIdx.x;
  float v = h0[i];
  unsigned short hb = f2b(v);
  plane[i] = hb;
  plane[65536 + i] = f2b(v - b2f(hb));
  if (blockIdx.x == 0 && threadIdx.x < 64) flags[threadIdx.x] = 0u;
}

// ---------------------------------------------------------------------------
// Distributed flag barrier (replaces cg::grid.sync; r1/r3/r5 all sat at
// ~17 us/step regardless of inner structure -> the shared cg barrier —
// single contended atomic counter + s_sleep backoff over 8 XCDs — is the
// dominant constant). Here: 64 independent flags (no RMW contention);
// arrive = release fence + per-WG flag store of generation `gen`; wait =
// wave 0 polls ALL flags with ONE coalesced 64-lane load + __all.
// Formal ordering: stores -> threadfence(release, all thr) -> syncthreads
// -> leader flag store; reader: poll -> syncthreads -> threadfence(acquire).
// ---------------------------------------------------------------------------
__device__ __forceinline__ void grid_flag_barrier(
    unsigned* flags, int g, unsigned gen, int tid)
{
  __threadfence();                 // release own writes to device scope
  __syncthreads();                 // edge: every thread's fence -> leader
  if (tid == 0)
    __hip_atomic_store(flags + g, gen, __ATOMIC_RELAXED, __HIP_MEMORY_SCOPE_AGENT);
  if (tid < 64){
    unsigned v;
    do {
      v = __hip_atomic_load(flags + tid, __ATOMIC_RELAXED, __HIP_MEMORY_SCOPE_AGENT);
    } while (!__all((int)(v >= gen)));
  }
  __syncthreads();                 // edge: poll wave -> all threads
  __threadfence();                 // acquire before reading remote data
}

// ---------------------------------------------------------------------------
// PERSISTENT recurrence, round 6: r5's DMA-staged quarters (unsinkable
// global_load_lds staging, proven correct) + distributed flag barrier
// instead of cg::grid.sync, + HQ row pitch padded 512->520 ushorts to cut
// the 16-way ds_read bank conflict to ~2-way (DMA dest stays linear per
// row; only the wave-uniform row base moves).
// Accumulation order (q asc, kk asc, va*whi, vl*whi, va*wlo) BIT-IDENTICAL
// to the proven engine. LDS: 66048 (Wsh) + 66560 (HQ) = 132608 B.
// ---------------------------------------------------------------------------
#define HQROW 520
__global__ __launch_bounds__(256) void rnn_persist(
    const _Float16* __restrict__ xts,       // [TS][NB*DH] fp16 input proj
    const float* __restrict__ Wh,           // [DH][DH] fp32
    const float* __restrict__ bh,           // [DH] fp32
    unsigned short* planes,                 // [2][2*65536] hi/lo, dbuf
    _Float16* __restrict__ hst,             // [TS][NB*DH] fp16 out states
    unsigned* flags)                        // [64] barrier flags (zeroed)
{
  __shared__ __align__(16) unsigned short WshH[16 * 1032];
  __shared__ __align__(16) unsigned short WshL[16 * 1032];
  __shared__ __align__(16) unsigned short HQ[64 * HQROW];
  const int g = blockIdx.x;
  const int tid = threadIdx.x;
  const int j0 = g * 16;
  const int w = tid >> 6, lane = tid & 63, quad = lane >> 4, lo4 = lane & 15;
  const int arow = 16 * w + lo4;
  const int col = j0 + lo4;
  const float bv = bh[col];

  // Stage Wh slice hi/lo into LDS ONCE.
  for (int idx = tid; idx < 16 * 256; idx += 256){
    int j = idx >> 8, c4 = idx & 255;
    f32x4 f = *(const f32x4*)(Wh + (size_t)(j0 + j) * DH + c4 * 4);
    u16x4 hi, lo;
    #pragma unroll
    for (int e = 0; e < 4; ++e){
      unsigned short h = f2b(f[e]);
      hi[e] = h;
      lo[e] = f2b(f[e] - b2f(h));
    }
    *(u16x4*)(WshH + j * 1032 + c4 * 4) = hi;
    *(u16x4*)(WshL + j * 1032 + c4 * 4) = lo;
  }
  __syncthreads();

  #pragma unroll 1
  for (int t = 0; t < TS; ++t){
    const unsigned short* hp = planes + (t & 1) * 131072;
    const unsigned short* lp = hp + 65536;
    unsigned short* pout = planes + ((t + 1) & 1) * 131072;
    const _Float16* xt = xts + (size_t)t * 65536;

    // x_t fragment (independent; waited on only in the epilogue)
    _Float16 xh[4];
    #pragma unroll
    for (int r = 0; r < 4; ++r)
      xh[r] = xt[(size_t)(16 * w + quad * 4 + r) * 1024 + col];

    f32x4 ah = {0.f, 0.f, 0.f, 0.f};

    #pragma unroll
    for (int q = 0; q < 4; ++q){
      // LDS quarter reusable (prev quarter's readers done; prev step via barrier)
      __syncthreads();
      // Stage quarter q: wave w stages rows [16w,16w+16). One issue per row:
      // lanes 0-31 <- hi plane, lanes 32-63 <- lo plane, 16 B each.
      {
        const unsigned short* pbase = (lane < 32) ? hp : lp;
        const unsigned short* src0 = pbase + q * 256 + (lane & 31) * 8;
        #pragma unroll
        for (int i = 0; i < 16; ++i){
          int r = 16 * w + i;
          gl_lds16(src0 + (size_t)r * 1024, HQ + r * HQROW);
        }
      }
      // Drain DMA (s_waitcnt vmcnt(0) before s_barrier) + visibility.
      __syncthreads();
      // Compute 8 chunk-pairs of this quarter (kk = q*8 + kkl, ascending).
      #pragma unroll
      for (int kkl = 0; kkl < 8; ++kkl){
        const int kk = q * 8 + kkl;
        V16 va, vl, whi, wlo;
        va.i = *(const i32x4*)(HQ + arow * HQROW + kkl * 32 + quad * 8);
        vl.i = *(const i32x4*)(HQ + arow * HQROW + 256 + kkl * 32 + quad * 8);
        whi.i = *(const i32x4*)(WshH + lo4 * 1032 + kk * 32 + quad * 8);
        wlo.i = *(const i32x4*)(WshL + lo4 * 1032 + kk * 32 + quad * 8);
        ah = __builtin_amdgcn_mfma_f32_16x16x32_bf16(va.b, whi.b, ah, 0, 0, 0);
        ah = __builtin_amdgcn_mfma_f32_16x16x32_bf16(vl.b, whi.b, ah, 0, 0, 0);
        ah = __builtin_amdgcn_mfma_f32_16x16x32_bf16(va.b, wlo.b, ah, 0, 0, 0);
      }
    }

    #pragma unroll
    for (int r = 0; r < 4; ++r){
      int row = 16 * w + quad * 4 + r;
      float v = ah[r] + (float)xh[r] + bv;
      v = tanhf(fmaxf(v, 0.0f));
      int off = row * 1024 + col;
      hst[(size_t)t * 65536 + off] = (_Float16)v;
      unsigned short hb = f2b(v);
      pout[off] = hb;
      pout[65536 + off] = f2b(v - b2f(hb));
    }

    // Release h_t, wait for whole grid (distributed flags, gen = t+1).
    grid_flag_barrier(flags, g, (unsigned)(t + 1), tid);
  }
}

// ---------------------------------------------------------------------------
// Workspace (~128.7 MB):
//   REG0 (64 MiB)   : inp_v fp16 -> out_v fp32 -> inp_m fp16
//   REG1 (64 MiB)   : hs_v fp16 -> out_t fp32 -> hs_m fp16
//   PLANES (512 KiB): h hi/lo bf16 double-buffered
//   FLAGS  (256 B)  : 64 barrier flags
// d_out: FP32 [N][T][O].
// ---------------------------------------------------------------------------
extern "C" void kernel_launch(void* const* d_in, const int* in_sizes, int n_in,
                              void* d_out, int out_size, void* d_ws, size_t ws_size,
                              hipStream_t stream)
{
  const float* data = (const float*)d_in[0];
  const float* h0v  = (const float*)d_in[1];
  const float* h0m  = (const float*)d_in[2];
  const float* Wi   = (const float*)d_in[3];
  const float* bi   = (const float*)d_in[4];
  const float* Wh   = (const float*)d_in[5];
  const float* bh   = (const float*)d_in[6];
  const float* Wo   = (const float*)d_in[7];
  const float* bo   = (const float*)d_in[8];
  const float* Wt   = (const float*)d_in[9];
  const float* bt   = (const float*)d_in[10];
  const float* Wi2  = (const float*)d_in[11];
  const float* bi2  = (const float*)d_in[12];
  const float* Wh2  = (const float*)d_in[13];
  const float* bh2  = (const float*)d_in[14];
  const float* Wo2  = (const float*)d_in[15];
  const float* bo2  = (const float*)d_in[16];

  char* base = (char*)d_ws;
  char* REG0 = base + 4096;
  char* REG1 = base + 4096 + (size_t)67108864;
  unsigned short* PLANES = (unsigned short*)(base + 4096 + (size_t)134217728);
  unsigned* FLAGS = (unsigned*)(base + 4096 + (size_t)134217728 + 524288);

  dim3 blk(256, 1, 1);

  // 1) inp_v[t,n,h] = data[n,t,:] @ Wi^T + bi  (A fp32-split, out fp16) -> REG0
  gemm_bt<0><<<dim3(8, 256, 1), blk, 0, stream>>>(data, Wi, bi, REG0, DI, DH, 1, 2);

  // 2) visual recurrence: ONE persistent cooperative kernel (512 steps)
  split_h0<<<dim3(256, 1, 1), blk, 0, stream>>>(h0v, PLANES, FLAGS);
  {
    const _Float16* xts = (const _Float16*)REG0;
    _Float16* hstp = (_Float16*)REG1;
    unsigned short* pl = PLANES;
    unsigned* fl = FLAGS;
    void* args[6] = { (void*)&xts, (void*)&Wh, (void*)&bh, (void*)&pl,
                      (void*)&hstp, (void*)&fl };
    hipLaunchCooperativeKernel((void*)rnn_persist, dim3(64, 1, 1), blk, args, 0, stream);
  }

  // 3) out_v[n,t,o] = hs_v[t,n,:] @ Wo^T + bo  (A fp16-split, out fp32) -> REG0
  gemm_bt<2><<<dim3(4, 256, 1), blk, 0, stream>>>(REG1, Wo, bo, REG0, DH, DO, 2, 0);

  // 4) out_t = retanh(out_v @ Wt^T + bt)       (A fp32-split, out fp32) -> REG1
  gemm_bt<0><<<dim3(4, 256, 1), blk, 0, stream>>>(REG0, Wt, bt, REG1, DO, DO, 0, 4);

  // 5) inp_m[t,n,h] = out_t[n,t,:] @ Wi2^T + bi2 (A fp32-split, out fp16) -> REG0
  gemm_bt<0><<<dim3(8, 256, 1), blk, 0, stream>>>(REG1, Wi2, bi2, REG0, DO, DH, 1, 2);

  // 6) motor recurrence: ONE persistent cooperative kernel
  split_h0<<<dim3(256, 1, 1), blk, 0, stream>>>(h0m, PLANES, FLAGS);
  {
    const _Float16* xts = (const _Float16*)REG0;
    _Float16* hstp = (_Float16*)REG1;
    unsigned short* pl = PLANES;
    unsigned* fl = FLAGS;
    void* args[6] = { (void*)&xts, (void*)&Wh2, (void*)&bh2, (void*)&pl,
                      (void*)&hstp, (void*)&fl };
    hipLaunchCooperativeKernel((void*)rnn_persist, dim3(64, 1, 1), blk, args, 0, stream);
  }

  // 7) out_m[n,t,o] = hs_m[t,n,:] @ Wo2^T + bo2 (A fp16-split, OUT FP32) -> d_out
  gemm_bt<2><<<dim3(4, 256, 1), blk, 0, stream>>>(REG1, Wo2, bo2, d_out, DH, DO, 2, 0);
}

// Round 7
// 9424.295 us; speedup vs baseline: 2.2911x; 2.2911x over previous
//
#include <hip/hip_runtime.h>

// Problem dims
#define NB 64     // batch N
#define TS 512    // timesteps T
#define DI 512    // input I
#define DH 1024   // hidden H
#define DO 512    // output O

typedef __bf16 bf16x8 __attribute__((ext_vector_type(8)));
typedef float f32x4 __attribute__((ext_vector_type(4)));
typedef _Float16 f16x4 __attribute__((ext_vector_type(4)));
typedef int i32x4 __attribute__((ext_vector_type(4)));
typedef unsigned short u16x4 __attribute__((ext_vector_type(4)));

union V16 { i32x4 i; bf16x8 b; };

__device__ __forceinline__ float b2f(unsigned short u){
  union { unsigned int u; float f; } c; c.u = ((unsigned int)u) << 16; return c.f;
}
__device__ __forceinline__ unsigned short f2b(float f){
  union { float f; unsigned int u; } c; c.f = f;
  unsigned int x = c.u;
  return (unsigned short)((x + 0x7fffu + ((x >> 16) & 1u)) >> 16);
}

// Async global->LDS DMA, 16 B/lane. No dest VGPR => compiler cannot sink it.
// LDS dest = wave-uniform base + lane*16 [m104]; global src is per-lane.
__device__ __forceinline__ void gl_lds16(const void* g, void* l){
  __builtin_amdgcn_global_load_lds((const unsigned int*)g, (unsigned int*)l, 16, 0, 0);
}

// ---------------------------------------------------------------------------
// C = A @ B^T + bias.  B: [NC][K] fp32 weights -> bf16-hi in LDS.
// AD: A dtype 0=fp32 (split hi/lo bf16, near-exact), 2=fp16 (split hi/lo,
// EXACT: fp16 mantissa 11b = bf16hi 8b + residual <=3b).
// mode (C-row q -> A-row remap): 0 rA=q | 1 C rows [T,N], A rows [N,T]
//   | 2 C rows [N,T], A rows [T,N]
// flags: bits0-1 out {0:f32, 2:f16}; bit2: retanh.
// Tile 128x128, BK=64, 256 thr, 2x2 waves of 64x64 (4x4 16x16x32 frags).
// Proven engine (unchanged).
// ---------------------------------------------------------------------------
template<int AD>
__global__ __launch_bounds__(256) void gemm_bt(
    const void* __restrict__ Ain,
    const float* __restrict__ B,
    const float* __restrict__ bias,
    void* __restrict__ Cout,
    int K, int NC, int mode, int flags)
{
  __shared__ __align__(16) unsigned short As[2 * 128 * 72];
  __shared__ __align__(16) unsigned short Bs[128 * 72];
  constexpr int AS2 = 128 * 72;
  const int tid = threadIdx.x;
  const int q0 = blockIdx.y * 128;
  const int j0 = blockIdx.x * 128;
  const int w = tid >> 6, lane = tid & 63, quad = lane >> 4, lo4 = lane & 15;
  const int wm = w >> 1, wn = w & 1;
  f32x4 acc[4][4] = {};
  const int nkt = K >> 6;

  for (int kt = 0; kt < nkt; ++kt){
    __syncthreads();
    // B tile: 128 rows x 64 k, fp32 -> bf16 hi
    #pragma unroll
    for (int it = 0; it < 8; ++it){
      int idx = tid + it * 256;            // 2048 float4 chunks
      int row = idx >> 4, c4 = idx & 15;
      f32x4 f = *(const f32x4*)(B + (size_t)(j0 + row) * K + kt * 64 + c4 * 4);
      u16x4 h;
      #pragma unroll
      for (int j = 0; j < 4; ++j) h[j] = f2b(f[j]);
      *(u16x4*)(Bs + row * 72 + c4 * 4) = h;
    }
    // A tile: split hi/lo
    #pragma unroll
    for (int it = 0; it < 8; ++it){
      int idx = tid + it * 256;
      int row = idx >> 4, c4 = idx & 15;
      int q = q0 + row;
      int rA = (mode == 0) ? q : (mode == 1 ? (q & 63) * TS + (q >> 6)
                                            : (q & 511) * NB + (q >> 9));
      float fv[4];
      if (AD == 0){
        f32x4 f = *(const f32x4*)((const float*)Ain + (size_t)rA * K + kt * 64 + c4 * 4);
        #pragma unroll
        for (int j = 0; j < 4; ++j) fv[j] = f[j];
      } else {
        f16x4 f = *(const f16x4*)((const _Float16*)Ain + (size_t)rA * K + kt * 64 + c4 * 4);
        #pragma unroll
        for (int j = 0; j < 4; ++j) fv[j] = (float)f[j];
      }
      u16x4 hi, lo;
      #pragma unroll
      for (int j = 0; j < 4; ++j){
        unsigned short h = f2b(fv[j]);
        hi[j] = h;
        lo[j] = f2b(fv[j] - b2f(h));
      }
      *(u16x4*)(As + row * 72 + c4 * 4) = hi;
      *(u16x4*)(As + AS2 + row * 72 + c4 * 4) = lo;
    }
    __syncthreads();
    #pragma unroll
    for (int kk = 0; kk < 2; ++kk){
      V16 b[4];
      #pragma unroll
      for (int n = 0; n < 4; ++n)
        b[n].i = *(const i32x4*)(Bs + (64 * wn + 16 * n + lo4) * 72 + kk * 32 + quad * 8);
      V16 a[4], a2[4];
      #pragma unroll
      for (int m = 0; m < 4; ++m){
        a[m].i = *(const i32x4*)(As + (64 * wm + 16 * m + lo4) * 72 + kk * 32 + quad * 8);
        a2[m].i = *(const i32x4*)(As + AS2 + (64 * wm + 16 * m + lo4) * 72 + kk * 32 + quad * 8);
      }
      #pragma unroll
      for (int m = 0; m < 4; ++m)
        #pragma unroll
        for (int n = 0; n < 4; ++n){
          acc[m][n] = __builtin_amdgcn_mfma_f32_16x16x32_bf16(a[m].b, b[n].b, acc[m][n], 0, 0, 0);
          acc[m][n] = __builtin_amdgcn_mfma_f32_16x16x32_bf16(a2[m].b, b[n].b, acc[m][n], 0, 0, 0);
        }
    }
  }
  // epilogue: C/D layout col=lane&15, row=quad*4+reg  [m89]
  const int od = flags & 3;
  #pragma unroll
  for (int n = 0; n < 4; ++n){
    int col = j0 + 64 * wn + 16 * n + lo4;
    float bv = bias[col];
    #pragma unroll
    for (int m = 0; m < 4; ++m){
      int row = q0 + 64 * wm + 16 * m + quad * 4;
      #pragma unroll
      for (int r = 0; r < 4; ++r){
        float v = acc[m][n][r] + bv;
        if (flags & 4) v = tanhf(fmaxf(v, 0.0f));
        size_t o = (size_t)(row + r) * NC + col;
        if (od == 0) ((float*)Cout)[o] = v;
        else         ((_Float16*)Cout)[o] = (_Float16)v;
      }
    }
  }
}

// ---------------------------------------------------------------------------
// h0 fp32 -> hi/lo bf16 planes (65536 elements) into plane buffer 0.
// ---------------------------------------------------------------------------
__global__ __launch_bounds__(256) void split_h0(
    const float* __restrict__ h0, unsigned short* __restrict__ plane)
{
  int i = blockIdx.x * 256 + threadIdx.x;
  float v = h0[i];
  unsigned short hb = f2b(v);
  plane[i] = hb;
  plane[65536 + i] = f2b(v - b2f(hb));
}

// ---------------------------------------------------------------------------
// Wh fp32 [DH][DH] -> global bf16 hi/lo planes, ONCE per RNN (removes the
// per-step fp32 re-read + ~16K f2b converts per WG of the baseline).
// Same f2b/b2f math on the same inputs -> bit-identical planes.
// ---------------------------------------------------------------------------
__global__ __launch_bounds__(256) void split_wh(
    const float* __restrict__ W,
    unsigned short* __restrict__ WH, unsigned short* __restrict__ WL)
{
  int i = (blockIdx.x * 256 + threadIdx.x) * 4;
  f32x4 f = *(const f32x4*)(W + i);
  u16x4 hi, lo;
  #pragma unroll
  for (int e = 0; e < 4; ++e){
    unsigned short h = f2b(f[e]);
    hi[e] = h;
    lo[e] = f2b(f[e] - b2f(h));
  }
  *(u16x4*)(WH + i) = hi;
  *(u16x4*)(WL + i) = lo;
}

// ---------------------------------------------------------------------------
// Per-step recurrence, round 7. Back to per-step launches (the only
// structure that beat 14 us/step: persistent floors at 17-20 us/step from
// the device-scope h-exchange, r1-r6). vs baseline rnn_step:
//   - Wh staged from PRE-SPLIT bf16 planes via global_load_lds (no fp32
//     re-read, no per-step f2b of 16K floats, unsinkable issue);
//   - h planes staged via the r5-proven DMA quarters (HQ, 520 pitch from
//     r6: 4x fewer bank conflicts) instead of serialized register loads;
//   - no fences/flags; kernel boundary provides cross-XCD visibility
//     (baseline-proven).
// Accumulation order (q asc, kk asc, va*whi, vl*whi, va*wlo), plane-split
// math and epilogue BIT-IDENTICAL to the proven engine.
// LDS: 2*16*1032*2 = 66048 (Wsh) + 64*520*2 = 66560 (HQ) = 132608 B.
// ---------------------------------------------------------------------------
#define HQROW 520
__global__ __launch_bounds__(256) void rnn_step2(
    const _Float16* __restrict__ xt,        // [NB][DH] fp16
    const unsigned short* __restrict__ WhH, // [DH][DH] bf16 hi plane
    const unsigned short* __restrict__ WhL, // [DH][DH] bf16 lo plane
    const float* __restrict__ bh,           // [DH]
    const unsigned short* __restrict__ pin, // [2][NB*DH] hi/lo
    unsigned short* __restrict__ pout,      // [2][NB*DH] hi/lo
    _Float16* __restrict__ hst)             // [NB][DH] fp16
{
  __shared__ __align__(16) unsigned short WshH[16 * 1032];
  __shared__ __align__(16) unsigned short WshL[16 * 1032];
  __shared__ __align__(16) unsigned short HQ[64 * HQROW];
  const int g = blockIdx.x;
  const int tid = threadIdx.x;
  const int j0 = g * 16;
  const int w = tid >> 6, lane = tid & 63, quad = lane >> 4, lo4 = lane & 15;
  const int arow = 16 * w + lo4;
  const int col = j0 + lo4;
  const float bv = bh[col];
  const unsigned short* hp = pin;
  const unsigned short* lp = pin + 65536;

  // Stage Wh slice (already-split bf16) into padded LDS via DMA:
  // 64 issues = 16 rows x {hi,lo} x {half0,half1}; idx = it*4 + w.
  // dest row base is wave-uniform; each issue covers 64 lanes x 16 B = 1 KB.
  #pragma unroll
  for (int it = 0; it < 16; ++it){
    int idx = it * 4 + w;
    int row  = idx >> 2;
    int pl   = (idx >> 1) & 1;
    int half = idx & 1;
    const unsigned short* src =
        (pl ? WhL : WhH) + (size_t)(j0 + row) * 1024 + half * 512 + lane * 8;
    unsigned short* dst = (pl ? WshL : WshH) + row * 1032 + half * 512;
    gl_lds16(src, dst);
  }

  // x_t fragment (independent; only needed in the epilogue)
  _Float16 xh[4];
  #pragma unroll
  for (int r = 0; r < 4; ++r)
    xh[r] = xt[(size_t)(16 * w + quad * 4 + r) * 1024 + col];

  f32x4 ah = {0.f, 0.f, 0.f, 0.f};

  #pragma unroll
  for (int q = 0; q < 4; ++q){
    if (q) __syncthreads();   // protect HQ readers of previous quarter
    // Stage quarter q: wave w stages rows [16w,16w+16). One issue per row:
    // lanes 0-31 <- hi plane, lanes 32-63 <- lo plane, 16 B each.
    {
      const unsigned short* pbase = (lane < 32) ? hp : lp;
      const unsigned short* src0 = pbase + q * 256 + (lane & 31) * 8;
      #pragma unroll
      for (int i = 0; i < 16; ++i){
        int r = 16 * w + i;
        gl_lds16(src0 + (size_t)r * 1024, HQ + r * HQROW);
      }
    }
    // Drain DMA (s_waitcnt vmcnt(0) before s_barrier; q=0 also drains Wsh).
    __syncthreads();
    // Compute 8 chunk-pairs of this quarter (kk = q*8 + kkl, ascending).
    #pragma unroll
    for (int kkl = 0; kkl < 8; ++kkl){
      const int kk = q * 8 + kkl;
      V16 va, vl, whi, wlo;
      va.i = *(const i32x4*)(HQ + arow * HQROW + kkl * 32 + quad * 8);
      vl.i = *(const i32x4*)(HQ + arow * HQROW + 256 + kkl * 32 + quad * 8);
      whi.i = *(const i32x4*)(WshH + lo4 * 1032 + kk * 32 + quad * 8);
      wlo.i = *(const i32x4*)(WshL + lo4 * 1032 + kk * 32 + quad * 8);
      ah = __builtin_amdgcn_mfma_f32_16x16x32_bf16(va.b, whi.b, ah, 0, 0, 0);
      ah = __builtin_amdgcn_mfma_f32_16x16x32_bf16(vl.b, whi.b, ah, 0, 0, 0);
      ah = __builtin_amdgcn_mfma_f32_16x16x32_bf16(va.b, wlo.b, ah, 0, 0, 0);
    }
  }

  #pragma unroll
  for (int r = 0; r < 4; ++r){
    int row = 16 * w + quad * 4 + r;
    float v = ah[r] + (float)xh[r] + bv;
    v = tanhf(fmaxf(v, 0.0f));
    int off = row * 1024 + col;
    hst[off] = (_Float16)v;
    unsigned short hb = f2b(v);
    pout[off] = hb;
    pout[65536 + off] = f2b(v - b2f(hb));
  }
}

// ---------------------------------------------------------------------------
// Workspace (~132.7 MB):
//   REG0 (64 MiB)   : inp_v fp16 -> out_v fp32 -> inp_m fp16
//   REG1 (64 MiB)   : hs_v fp16 -> out_t fp32 -> hs_m fp16
//   PLANES (512 KiB): h hi/lo bf16 double-buffered
//   WP (4 MiB)      : Wh bf16 hi/lo planes (reused for Wh2)
// d_out: FP32 [N][T][O].
// ---------------------------------------------------------------------------
extern "C" void kernel_launch(void* const* d_in, const int* in_sizes, int n_in,
                              void* d_out, int out_size, void* d_ws, size_t ws_size,
                              hipStream_t stream)
{
  const float* data = (const float*)d_in[0];
  const float* h0v  = (const float*)d_in[1];
  const float* h0m  = (const float*)d_in[2];
  const float* Wi   = (const float*)d_in[3];
  const float* bi   = (const float*)d_in[4];
  const float* Wh   = (const float*)d_in[5];
  const float* bh   = (const float*)d_in[6];
  const float* Wo   = (const float*)d_in[7];
  const float* bo   = (const float*)d_in[8];
  const float* Wt   = (const float*)d_in[9];
  const float* bt   = (const float*)d_in[10];
  const float* Wi2  = (const float*)d_in[11];
  const float* bi2  = (const float*)d_in[12];
  const float* Wh2  = (const float*)d_in[13];
  const float* bh2  = (const float*)d_in[14];
  const float* Wo2  = (const float*)d_in[15];
  const float* bo2  = (const float*)d_in[16];

  char* base = (char*)d_ws;
  char* REG0 = base + 4096;
  char* REG1 = base + 4096 + (size_t)67108864;
  unsigned short* PLANES = (unsigned short*)(base + 4096 + (size_t)134217728);
  unsigned short* WPH = (unsigned short*)(base + 4096 + (size_t)134217728 + 524288);
  unsigned short* WPL = WPH + 1024 * 1024;

  dim3 blk(256, 1, 1);

  // 1) inp_v[t,n,h] = data[n,t,:] @ Wi^T + bi  (A fp32-split, out fp16) -> REG0
  gemm_bt<0><<<dim3(8, 256, 1), blk, 0, stream>>>(data, Wi, bi, REG0, DI, DH, 1, 2);

  // 2) visual recurrence: per-step launches, pre-split weights
  split_wh<<<dim3(1024, 1, 1), blk, 0, stream>>>(Wh, WPH, WPL);
  split_h0<<<dim3(256, 1, 1), blk, 0, stream>>>(h0v, PLANES);
  for (int t = 0; t < TS; ++t){
    const unsigned short* pin = PLANES + (t & 1) * 131072;
    unsigned short* pout = PLANES + ((t + 1) & 1) * 131072;
    rnn_step2<<<dim3(64, 1, 1), blk, 0, stream>>>(
        (const _Float16*)REG0 + (size_t)t * 65536, WPH, WPL, bh, pin, pout,
        (_Float16*)REG1 + (size_t)t * 65536);
  }

  // 3) out_v[n,t,o] = hs_v[t,n,:] @ Wo^T + bo  (A fp16-split, out fp32) -> REG0
  gemm_bt<2><<<dim3(4, 256, 1), blk, 0, stream>>>(REG1, Wo, bo, REG0, DH, DO, 2, 0);

  // 4) out_t = retanh(out_v @ Wt^T + bt)       (A fp32-split, out fp32) -> REG1
  gemm_bt<0><<<dim3(4, 256, 1), blk, 0, stream>>>(REG0, Wt, bt, REG1, DO, DO, 0, 4);

  // 5) inp_m[t,n,h] = out_t[n,t,:] @ Wi2^T + bi2 (A fp32-split, out fp16) -> REG0
  gemm_bt<0><<<dim3(8, 256, 1), blk, 0, stream>>>(REG1, Wi2, bi2, REG0, DO, DH, 1, 2);

  // 6) motor recurrence
  split_wh<<<dim3(1024, 1, 1), blk, 0, stream>>>(Wh2, WPH, WPL);
  split_h0<<<dim3(256, 1, 1), blk, 0, stream>>>(h0m, PLANES);
  for (int t = 0; t < TS; ++t){
    const unsigned short* pin = PLANES + (t & 1) * 131072;
    unsigned short* pout = PLANES + ((t + 1) & 1) * 131072;
    rnn_step2<<<dim3(64, 1, 1), blk, 0, stream>>>(
        (const _Float16*)REG0 + (size_t)t * 65536, WPH, WPL, bh2, pin, pout,
        (_Float16*)REG1 + (size_t)t * 65536);
  }

  // 7) out_m[n,t,o] = hs_m[t,n,:] @ Wo2^T + bo2 (A fp16-split, OUT FP32) -> d_out
  gemm_bt<2><<<dim3(4, 256, 1), blk, 0, stream>>>(REG1, Wo2, bo2, d_out, DH, DO, 2, 0);
}

// Round 8
// 6518.349 us; speedup vs baseline: 3.3126x; 1.4458x over previous
//
#include <hip/hip_runtime.h>

// Problem dims
#define NB 64     // batch N
#define TS 512    // timesteps T
#define DI 512    // input I
#define DH 1024   // hidden H
#define DO 512    // output O

typedef __bf16 bf16x8 __attribute__((ext_vector_type(8)));
typedef float f32x4 __attribute__((ext_vector_type(4)));
typedef _Float16 f16x4 __attribute__((ext_vector_type(4)));
typedef int i32x4 __attribute__((ext_vector_type(4)));
typedef unsigned short u16x4 __attribute__((ext_vector_type(4)));

union V16 { i32x4 i; bf16x8 b; };

__device__ __forceinline__ float b2f(unsigned short u){
  union { unsigned int u; float f; } c; c.u = ((unsigned int)u) << 16; return c.f;
}
__device__ __forceinline__ unsigned short f2b(float f){
  union { float f; unsigned int u; } c; c.f = f;
  unsigned int x = c.u;
  return (unsigned short)((x + 0x7fffu + ((x >> 16) & 1u)) >> 16);
}

// Async global->LDS DMA, 16 B/lane. No dest VGPR => compiler cannot sink it.
// LDS dest = wave-uniform base + lane*16 [m104]; global src is per-lane.
__device__ __forceinline__ void gl_lds16(const void* g, void* l){
  __builtin_amdgcn_global_load_lds((const unsigned int*)g, (unsigned int*)l, 16, 0, 0);
}

// ---------------------------------------------------------------------------
// C = A @ B^T + bias.  B: [NC][K] fp32 weights -> bf16-hi in LDS.
// AD: A dtype 0=fp32 (split hi/lo bf16, near-exact), 2=fp16 (split hi/lo,
// EXACT: fp16 mantissa 11b = bf16hi 8b + residual <=3b).
// mode (C-row q -> A-row remap): 0 rA=q | 1 C rows [T,N], A rows [N,T]
//   | 2 C rows [N,T], A rows [T,N]
// flags: bits0-1 out {0:f32, 2:f16}; bit2: retanh.
// Tile 128x128, BK=64, 256 thr, 2x2 waves of 64x64 (4x4 16x16x32 frags).
// Proven engine (unchanged).
// ---------------------------------------------------------------------------
template<int AD>
__global__ __launch_bounds__(256) void gemm_bt(
    const void* __restrict__ Ain,
    const float* __restrict__ B,
    const float* __restrict__ bias,
    void* __restrict__ Cout,
    int K, int NC, int mode, int flags)
{
  __shared__ __align__(16) unsigned short As[2 * 128 * 72];
  __shared__ __align__(16) unsigned short Bs[128 * 72];
  constexpr int AS2 = 128 * 72;
  const int tid = threadIdx.x;
  const int q0 = blockIdx.y * 128;
  const int j0 = blockIdx.x * 128;
  const int w = tid >> 6, lane = tid & 63, quad = lane >> 4, lo4 = lane & 15;
  const int wm = w >> 1, wn = w & 1;
  f32x4 acc[4][4] = {};
  const int nkt = K >> 6;

  for (int kt = 0; kt < nkt; ++kt){
    __syncthreads();
    // B tile: 128 rows x 64 k, fp32 -> bf16 hi
    #pragma unroll
    for (int it = 0; it < 8; ++it){
      int idx = tid + it * 256;            // 2048 float4 chunks
      int row = idx >> 4, c4 = idx & 15;
      f32x4 f = *(const f32x4*)(B + (size_t)(j0 + row) * K + kt * 64 + c4 * 4);
      u16x4 h;
      #pragma unroll
      for (int j = 0; j < 4; ++j) h[j] = f2b(f[j]);
      *(u16x4*)(Bs + row * 72 + c4 * 4) = h;
    }
    // A tile: split hi/lo
    #pragma unroll
    for (int it = 0; it < 8; ++it){
      int idx = tid + it * 256;
      int row = idx >> 4, c4 = idx & 15;
      int q = q0 + row;
      int rA = (mode == 0) ? q : (mode == 1 ? (q & 63) * TS + (q >> 6)
                                            : (q & 511) * NB + (q >> 9));
      float fv[4];
      if (AD == 0){
        f32x4 f = *(const f32x4*)((const float*)Ain + (size_t)rA * K + kt * 64 + c4 * 4);
        #pragma unroll
        for (int j = 0; j < 4; ++j) fv[j] = f[j];
      } else {
        f16x4 f = *(const f16x4*)((const _Float16*)Ain + (size_t)rA * K + kt * 64 + c4 * 4);
        #pragma unroll
        for (int j = 0; j < 4; ++j) fv[j] = (float)f[j];
      }
      u16x4 hi, lo;
      #pragma unroll
      for (int j = 0; j < 4; ++j){
        unsigned short h = f2b(fv[j]);
        hi[j] = h;
        lo[j] = f2b(fv[j] - b2f(h));
      }
      *(u16x4*)(As + row * 72 + c4 * 4) = hi;
      *(u16x4*)(As + AS2 + row * 72 + c4 * 4) = lo;
    }
    __syncthreads();
    #pragma unroll
    for (int kk = 0; kk < 2; ++kk){
      V16 b[4];
      #pragma unroll
      for (int n = 0; n < 4; ++n)
        b[n].i = *(const i32x4*)(Bs + (64 * wn + 16 * n + lo4) * 72 + kk * 32 + quad * 8);
      V16 a[4], a2[4];
      #pragma unroll
      for (int m = 0; m < 4; ++m){
        a[m].i = *(const i32x4*)(As + (64 * wm + 16 * m + lo4) * 72 + kk * 32 + quad * 8);
        a2[m].i = *(const i32x4*)(As + AS2 + (64 * wm + 16 * m + lo4) * 72 + kk * 32 + quad * 8);
      }
      #pragma unroll
      for (int m = 0; m < 4; ++m)
        #pragma unroll
        for (int n = 0; n < 4; ++n){
          acc[m][n] = __builtin_amdgcn_mfma_f32_16x16x32_bf16(a[m].b, b[n].b, acc[m][n], 0, 0, 0);
          acc[m][n] = __builtin_amdgcn_mfma_f32_16x16x32_bf16(a2[m].b, b[n].b, acc[m][n], 0, 0, 0);
        }
    }
  }
  // epilogue: C/D layout col=lane&15, row=quad*4+reg  [m89]
  const int od = flags & 3;
  #pragma unroll
  for (int n = 0; n < 4; ++n){
    int col = j0 + 64 * wn + 16 * n + lo4;
    float bv = bias[col];
    #pragma unroll
    for (int m = 0; m < 4; ++m){
      int row = q0 + 64 * wm + 16 * m + quad * 4;
      #pragma unroll
      for (int r = 0; r < 4; ++r){
        float v = acc[m][n][r] + bv;
        if (flags & 4) v = tanhf(fmaxf(v, 0.0f));
        size_t o = (size_t)(row + r) * NC + col;
        if (od == 0) ((float*)Cout)[o] = v;
        else         ((_Float16*)Cout)[o] = (_Float16)v;
      }
    }
  }
}

// ---------------------------------------------------------------------------
// h0 fp32 -> hi/lo bf16 planes (65536 elements) into plane buffer 0.
// ---------------------------------------------------------------------------
__global__ __launch_bounds__(256) void split_h0(
    const float* __restrict__ h0, unsigned short* __restrict__ plane)
{
  int i = blockIdx.x * 256 + threadIdx.x;
  float v = h0[i];
  unsigned short hb = f2b(v);
  plane[i] = hb;
  plane[65536 + i] = f2b(v - b2f(hb));
}

// ---------------------------------------------------------------------------
// Wh fp32 [DH][DH] -> global bf16 hi/lo planes, ONCE per RNN (removes the
// per-step fp32 re-read + ~16K f2b converts per WG of the baseline).
// Same f2b/b2f math on the same inputs -> bit-identical planes.
// ---------------------------------------------------------------------------
__global__ __launch_bounds__(256) void split_wh(
    const float* __restrict__ W,
    unsigned short* __restrict__ WH, unsigned short* __restrict__ WL)
{
  int i = (blockIdx.x * 256 + threadIdx.x) * 4;
  f32x4 f = *(const f32x4*)(W + i);
  u16x4 hi, lo;
  #pragma unroll
  for (int e = 0; e < 4; ++e){
    unsigned short h = f2b(f[e]);
    hi[e] = h;
    lo[e] = f2b(f[e] - b2f(h));
  }
  *(u16x4*)(WH + i) = hi;
  *(u16x4*)(WL + i) = lo;
}

// ---------------------------------------------------------------------------
// Per-step recurrence, round 8: 1-WAVE WORKGROUPS, 256 WGs (64 col-groups x
// 4 batch-row-groups) -> all 256 CUs busy (r7 used only 64) and each WG
// stages only what its wave consumes: 16 batch rows x full k of h hi/lo
// (64 KB) + its 16-row Wh slice (64 KB) = 128 KB (r7: 320 KB). All staging
// is DMA (global_load_lds, unsinkable), batched behind ONE barrier.
// Per-output-element operands, fragment layout, and accumulation order
// (kk asc, va*whi, vl*whi, va*wlo) BIT-IDENTICAL to the proven engine —
// only the WG-to-work mapping changed.
// LDS: 4 x 16x1032x2B = 132096 B. Pitch 1032 (stride = 4 banks: rows
// r, r+8 collide -> 2-way, free per m136).
// ---------------------------------------------------------------------------
#define WPITCH 1032
__global__ __launch_bounds__(64) void rnn_step3(
    const _Float16* __restrict__ xt,        // [NB][DH] fp16
    const unsigned short* __restrict__ WhH, // [DH][DH] bf16 hi plane
    const unsigned short* __restrict__ WhL, // [DH][DH] bf16 lo plane
    const float* __restrict__ bh,           // [DH]
    const unsigned short* __restrict__ pin, // [2][NB*DH] hi/lo
    unsigned short* __restrict__ pout,      // [2][NB*DH] hi/lo
    _Float16* __restrict__ hst)             // [NB][DH] fp16
{
  __shared__ __align__(16) unsigned short WshH[16 * WPITCH];
  __shared__ __align__(16) unsigned short WshL[16 * WPITCH];
  __shared__ __align__(16) unsigned short HQH[16 * WPITCH];
  __shared__ __align__(16) unsigned short HQL[16 * WPITCH];
  const int g  = blockIdx.x;      // col group 0..63
  const int rb = blockIdx.y;      // batch row group 0..3
  const int lane = threadIdx.x;   // 0..63 (one wave)
  const int quad = lane >> 4, lo4 = lane & 15;
  const int j0 = g * 16;
  const int r0 = rb * 16;
  const int col = j0 + lo4;
  const float bv = bh[col];
  const unsigned short* hp = pin;
  const unsigned short* lp = pin + 65536;

  // Stage Wh slice (pre-split bf16): 16 rows x {hi,lo} x {half} = 64 issues.
  #pragma unroll
  for (int row = 0; row < 16; ++row){
    #pragma unroll
    for (int half = 0; half < 2; ++half){
      gl_lds16(WhH + (size_t)(j0 + row) * 1024 + half * 512 + lane * 8,
               WshH + row * WPITCH + half * 512);
      gl_lds16(WhL + (size_t)(j0 + row) * 1024 + half * 512 + lane * 8,
               WshL + row * WPITCH + half * 512);
    }
  }
  // Stage h rows r0..r0+15 (hi+lo, full k): 64 issues.
  #pragma unroll
  for (int row = 0; row < 16; ++row){
    #pragma unroll
    for (int half = 0; half < 2; ++half){
      gl_lds16(hp + (size_t)(r0 + row) * 1024 + half * 512 + lane * 8,
               HQH + row * WPITCH + half * 512);
      gl_lds16(lp + (size_t)(r0 + row) * 1024 + half * 512 + lane * 8,
               HQL + row * WPITCH + half * 512);
    }
  }

  // x_t fragment (independent; only needed in the epilogue)
  _Float16 xh[4];
  #pragma unroll
  for (int r = 0; r < 4; ++r)
    xh[r] = xt[(size_t)(r0 + quad * 4 + r) * 1024 + col];

  // One drain: s_waitcnt vmcnt(0) before s_barrier covers all 128 DMAs.
  __syncthreads();

  f32x4 ah = {0.f, 0.f, 0.f, 0.f};
  #pragma unroll
  for (int kk = 0; kk < 32; ++kk){
    V16 va, vl, whi, wlo;
    va.i  = *(const i32x4*)(HQH  + lo4 * WPITCH + kk * 32 + quad * 8);
    vl.i  = *(const i32x4*)(HQL  + lo4 * WPITCH + kk * 32 + quad * 8);
    whi.i = *(const i32x4*)(WshH + lo4 * WPITCH + kk * 32 + quad * 8);
    wlo.i = *(const i32x4*)(WshL + lo4 * WPITCH + kk * 32 + quad * 8);
    ah = __builtin_amdgcn_mfma_f32_16x16x32_bf16(va.b, whi.b, ah, 0, 0, 0);
    ah = __builtin_amdgcn_mfma_f32_16x16x32_bf16(vl.b, whi.b, ah, 0, 0, 0);
    ah = __builtin_amdgcn_mfma_f32_16x16x32_bf16(va.b, wlo.b, ah, 0, 0, 0);
  }

  #pragma unroll
  for (int r = 0; r < 4; ++r){
    int row = r0 + quad * 4 + r;
    float v = ah[r] + (float)xh[r] + bv;
    v = tanhf(fmaxf(v, 0.0f));
    int off = row * 1024 + col;
    hst[off] = (_Float16)v;
    unsigned short hb = f2b(v);
    pout[off] = hb;
    pout[65536 + off] = f2b(v - b2f(hb));
  }
}

// ---------------------------------------------------------------------------
// Workspace (~132.7 MB):
//   REG0 (64 MiB)   : inp_v fp16 -> out_v fp32 -> inp_m fp16
//   REG1 (64 MiB)   : hs_v fp16 -> out_t fp32 -> hs_m fp16
//   PLANES (512 KiB): h hi/lo bf16 double-buffered
//   WP (4 MiB)      : Wh bf16 hi/lo planes (reused for Wh2)
// d_out: FP32 [N][T][O].
// ---------------------------------------------------------------------------
extern "C" void kernel_launch(void* const* d_in, const int* in_sizes, int n_in,
                              void* d_out, int out_size, void* d_ws, size_t ws_size,
                              hipStream_t stream)
{
  const float* data = (const float*)d_in[0];
  const float* h0v  = (const float*)d_in[1];
  const float* h0m  = (const float*)d_in[2];
  const float* Wi   = (const float*)d_in[3];
  const float* bi   = (const float*)d_in[4];
  const float* Wh   = (const float*)d_in[5];
  const float* bh   = (const float*)d_in[6];
  const float* Wo   = (const float*)d_in[7];
  const float* bo   = (const float*)d_in[8];
  const float* Wt   = (const float*)d_in[9];
  const float* bt   = (const float*)d_in[10];
  const float* Wi2  = (const float*)d_in[11];
  const float* bi2  = (const float*)d_in[12];
  const float* Wh2  = (const float*)d_in[13];
  const float* bh2  = (const float*)d_in[14];
  const float* Wo2  = (const float*)d_in[15];
  const float* bo2  = (const float*)d_in[16];

  char* base = (char*)d_ws;
  char* REG0 = base + 4096;
  char* REG1 = base + 4096 + (size_t)67108864;
  unsigned short* PLANES = (unsigned short*)(base + 4096 + (size_t)134217728);
  unsigned short* WPH = (unsigned short*)(base + 4096 + (size_t)134217728 + 524288);
  unsigned short* WPL = WPH + 1024 * 1024;

  dim3 blk(256, 1, 1);
  dim3 blk64(64, 1, 1);

  // 1) inp_v[t,n,h] = data[n,t,:] @ Wi^T + bi  (A fp32-split, out fp16) -> REG0
  gemm_bt<0><<<dim3(8, 256, 1), blk, 0, stream>>>(data, Wi, bi, REG0, DI, DH, 1, 2);

  // 2) visual recurrence: per-step launches, pre-split weights, 1-wave WGs
  split_wh<<<dim3(1024, 1, 1), blk, 0, stream>>>(Wh, WPH, WPL);
  split_h0<<<dim3(256, 1, 1), blk, 0, stream>>>(h0v, PLANES);
  for (int t = 0; t < TS; ++t){
    const unsigned short* pin = PLANES + (t & 1) * 131072;
    unsigned short* pout = PLANES + ((t + 1) & 1) * 131072;
    rnn_step3<<<dim3(64, 4, 1), blk64, 0, stream>>>(
        (const _Float16*)REG0 + (size_t)t * 65536, WPH, WPL, bh, pin, pout,
        (_Float16*)REG1 + (size_t)t * 65536);
  }

  // 3) out_v[n,t,o] = hs_v[t,n,:] @ Wo^T + bo  (A fp16-split, out fp32) -> REG0
  gemm_bt<2><<<dim3(4, 256, 1), blk, 0, stream>>>(REG1, Wo, bo, REG0, DH, DO, 2, 0);

  // 4) out_t = retanh(out_v @ Wt^T + bt)       (A fp32-split, out fp32) -> REG1
  gemm_bt<0><<<dim3(4, 256, 1), blk, 0, stream>>>(REG0, Wt, bt, REG1, DO, DO, 0, 4);

  // 5) inp_m[t,n,h] = out_t[n,t,:] @ Wi2^T + bi2 (A fp32-split, out fp16) -> REG0
  gemm_bt<0><<<dim3(8, 256, 1), blk, 0, stream>>>(REG1, Wi2, bi2, REG0, DO, DH, 1, 2);

  // 6) motor recurrence
  split_wh<<<dim3(1024, 1, 1), blk, 0, stream>>>(Wh2, WPH, WPL);
  split_h0<<<dim3(256, 1, 1), blk, 0, stream>>>(h0m, PLANES);
  for (int t = 0; t < TS; ++t){
    const unsigned short* pin = PLANES + (t & 1) * 131072;
    unsigned short* pout = PLANES + ((t + 1) & 1) * 131072;
    rnn_step3<<<dim3(64, 4, 1), blk64, 0, stream>>>(
        (const _Float16*)REG0 + (size_t)t * 65536, WPH, WPL, bh2, pin, pout,
        (_Float16*)REG1 + (size_t)t * 65536);
  }

  // 7) out_m[n,t,o] = hs_m[t,n,:] @ Wo2^T + bo2 (A fp16-split, OUT FP32) -> d_out
  gemm_bt<2><<<dim3(4, 256, 1), blk, 0, stream>>>(REG1, Wo2, bo2, d_out, DH, DO, 2, 0);
}